// Round 1
// baseline (94687.708 us; speedup 1.0000x reference)
//
#include <hip/hip_runtime.h>
#include <cstdint>
#include <cstddef>

// ============================================================================
// PointerNet: encoder LSTM (B=512,S=256,D=2,H=256) + autoregressive pointer
// decode with jax.random.categorical sampling (threefry2x32, key 42).
// Output: int32 indices [512][256]. Trajectory must match reference exactly.
//
// Structure: 1 memset + 1 repack kernel + 1 persistent cooperative kernel.
// Grid 256 blocks x 512 threads = 64 independent groups (8 batches each) x
// 4 slices (64 units / 64 score-positions each). Only the 4 sibling blocks of
// a group synchronize (device-scope atomic barrier) -> groups drift, overlap.
// ============================================================================

#define THREEFRY_PARTITIONABLE 1   // modern JAX default; flip to 0 for legacy

#define WS_CNT_OFF    (1u << 20)                    // [64 groups][32] uint
#define WS_PART_OFF   ((1u << 20) + 8192u)          // [64][8][4] uint2
#define WS_ENCW4_OFF  (2u << 20)                    // [256 k][256 u][4 g] f32
#define WS_DECWI4_OFF (3u << 20)
#define WS_DECWH4_OFF (4u << 20)
#define WS_ENCK4_OFF  (5u << 20)                    // [512 b][64 k4][256 s][4] f32
#define WS_NEEDED     ((size_t)(5u << 20) + (size_t)512 * 64 * 256 * 16)

__device__ __forceinline__ unsigned rotl32(unsigned x, int r) {
  return (x << r) | (x >> (32 - r));
}
__device__ __forceinline__ float sigm(float x) { return 1.f / (1.f + expf(-x)); }

// Threefry-2x32, 20 rounds (matches jax._src.prng rotation schedule exactly)
__device__ __forceinline__ void tf2(unsigned k0, unsigned k1,
                                    unsigned& x0, unsigned& x1) {
  const unsigned k2 = k0 ^ k1 ^ 0x1BD11BDAu;
  x0 += k0; x1 += k1;
  x0 += x1; x1 = rotl32(x1, 13); x1 ^= x0;
  x0 += x1; x1 = rotl32(x1, 15); x1 ^= x0;
  x0 += x1; x1 = rotl32(x1, 26); x1 ^= x0;
  x0 += x1; x1 = rotl32(x1,  6); x1 ^= x0;
  x0 += k1; x1 += k2 + 1u;
  x0 += x1; x1 = rotl32(x1, 17); x1 ^= x0;
  x0 += x1; x1 = rotl32(x1, 29); x1 ^= x0;
  x0 += x1; x1 = rotl32(x1, 16); x1 ^= x0;
  x0 += x1; x1 = rotl32(x1, 24); x1 ^= x0;
  x0 += k2; x1 += k0 + 2u;
  x0 += x1; x1 = rotl32(x1, 13); x1 ^= x0;
  x0 += x1; x1 = rotl32(x1, 15); x1 ^= x0;
  x0 += x1; x1 = rotl32(x1, 26); x1 ^= x0;
  x0 += x1; x1 = rotl32(x1,  6); x1 ^= x0;
  x0 += k0; x1 += k1 + 3u;
  x0 += x1; x1 = rotl32(x1, 17); x1 ^= x0;
  x0 += x1; x1 = rotl32(x1, 29); x1 ^= x0;
  x0 += x1; x1 = rotl32(x1, 16); x1 ^= x0;
  x0 += x1; x1 = rotl32(x1, 24); x1 ^= x0;
  x0 += k1; x1 += k2 + 4u;
  x0 += x1; x1 = rotl32(x1, 13); x1 ^= x0;
  x0 += x1; x1 = rotl32(x1, 15); x1 ^= x0;
  x0 += x1; x1 = rotl32(x1, 26); x1 ^= x0;
  x0 += x1; x1 = rotl32(x1,  6); x1 ^= x0;
  x0 += k2; x1 += k0 + 5u;
}

// 4-block group barrier: monotonic counter (memset to 0 each launch).
__device__ __forceinline__ void group_barrier(unsigned* cnt, int tid, int* gen) {
  __threadfence();          // release: make this block's global writes visible
  __syncthreads();
  if (tid == 0) {
    const unsigned tgt = 4u * (unsigned)(++(*gen));
    atomicAdd(cnt, 1u);     // device-scope by default
    while (__hip_atomic_load(cnt, __ATOMIC_RELAXED, __HIP_MEMORY_SCOPE_AGENT) < tgt)
      __builtin_amdgcn_s_sleep(4);
  }
  __syncthreads();
  __threadfence();          // acquire: invalidate caches before reading siblings
}

// Repack W [1024 rows][256 k] row-major -> [k][u][gate] float4-friendly.
__global__ void repack_k(const float* __restrict__ eWh,
                         const float* __restrict__ dWi,
                         const float* __restrict__ dWh,
                         float* __restrict__ ws) {
  float* encW4 = (float*)((char*)ws + WS_ENCW4_OFF);
  float* decWi4 = (float*)((char*)ws + WS_DECWI4_OFF);
  float* decWh4 = (float*)((char*)ws + WS_DECWH4_OFF);
  const int n = blockIdx.x * blockDim.x + threadIdx.x;   // 65536 = 256k x 256u
  if (n >= 65536) return;
  const int k = n >> 8, u = n & 255;
#pragma unroll
  for (int g = 0; g < 4; ++g) {
    const int src = ((g << 8) + u) * 256 + k;
    const int dst = (n << 2) + g;
    encW4[dst] = eWh[src];
    decWi4[dst] = dWi[src];
    decWh4[dst] = dWh[src];
  }
}

__global__ void __launch_bounds__(512, 1)
ptrnet_kernel(const float* __restrict__ inp,    // [512][256][2]
              const float* __restrict__ eWi,    // [1024][2]
              const float* __restrict__ eBi, const float* __restrict__ eBh,
              const float* __restrict__ dBi, const float* __restrict__ dBh,
              int* __restrict__ out,            // [512][256]
              float* __restrict__ ws) {
  const int tid = threadIdx.x;
  const int w = tid >> 6;          // wave 0..7  <-> batch within group
  const int l = tid & 63;          // lane       <-> unit / score position
  const int g = blockIdx.x >> 2;   // group 0..63 (8 batches)
  const int us = blockIdx.x & 3;   // slice 0..3 (64 units / 64 s-positions)
  const int b = (g << 3) + w;
  const int u = (us << 6) + l;

  float* hbuf0 = ws;               // h state double buffer [512][256] each
  float* hbuf1 = ws + 512 * 256;
  unsigned* cnt = (unsigned*)((char*)ws + WS_CNT_OFF) + g * 32;
  uint2* part = (uint2*)((char*)ws + WS_PART_OFF);
  const float4* encW4 = (const float4*)((char*)ws + WS_ENCW4_OFF);
  const float4* decWi4 = (const float4*)((char*)ws + WS_DECWI4_OFF);
  const float4* decWh4 = (const float4*)((char*)ws + WS_DECWH4_OFF);
  float4* encK4 = (float4*)((char*)ws + WS_ENCK4_OFF);

  __shared__ float4 hs4[512];           // [8 batch][64 k4]
  __shared__ float4 din4[512];          // dec_in staged, same layout
  __shared__ unsigned char maskS[8][64];
  __shared__ int idxS[8];

  // encoder per-lane constants (bias sums + W_ih rows for unit u)
  const float ebi_ = eBi[u] + eBh[u];
  const float ebf_ = eBi[256 + u] + eBh[256 + u];
  const float ebg_ = eBi[512 + u] + eBh[512 + u];
  const float ebo_ = eBi[768 + u] + eBh[768 + u];
  const float wxi0 = eWi[2 * u], wxi1 = eWi[2 * u + 1];
  const float wxf0 = eWi[2 * (256 + u)], wxf1 = eWi[2 * (256 + u) + 1];
  const float wxg0 = eWi[2 * (512 + u)], wxg1 = eWi[2 * (512 + u) + 1];
  const float wxo0 = eWi[2 * (768 + u)], wxo1 = eWi[2 * (768 + u) + 1];

  float c = 0.f;     // cell state for (b,u) lives here the whole kernel
  int gen = 0;
  int p = 0;         // h read-buffer parity

  // ---------------- encoder: 256 steps ----------------
  for (int t = 0; t < 256; ++t) {
    const float4* hrd = (const float4*)(p ? hbuf1 : hbuf0);
    hs4[tid] = hrd[(g << 9) + tid];
    __syncthreads();
    const float2 xv = *(const float2*)(inp + ((b << 8) + t) * 2);
    float ai = ebi_ + wxi0 * xv.x + wxi1 * xv.y;
    float af = ebf_ + wxf0 * xv.x + wxf1 * xv.y;
    float ag = ebg_ + wxg0 * xv.x + wxg1 * xv.y;
    float ao = ebo_ + wxo0 * xv.x + wxo1 * xv.y;
    const float4* Wp = encW4 + u;           // encW4[(k*256+u)]
    const float4* hq = hs4 + (w << 6);
#pragma unroll 4
    for (int k4 = 0; k4 < 64; ++k4) {
      const float4 hv = hq[k4];
      const float4 w0 = Wp[((k4 * 4 + 0) << 8)];
      const float4 w1 = Wp[((k4 * 4 + 1) << 8)];
      const float4 w2 = Wp[((k4 * 4 + 2) << 8)];
      const float4 w3 = Wp[((k4 * 4 + 3) << 8)];
      ai += w0.x * hv.x + w1.x * hv.y + w2.x * hv.z + w3.x * hv.w;
      af += w0.y * hv.x + w1.y * hv.y + w2.y * hv.z + w3.y * hv.w;
      ag += w0.z * hv.x + w1.z * hv.y + w2.z * hv.z + w3.z * hv.w;
      ao += w0.w * hv.x + w1.w * hv.y + w2.w * hv.z + w3.w * hv.w;
    }
    const float iv = sigm(ai), fv = sigm(af), gv = tanhf(ag), ov = sigm(ao);
    c = fv * c + iv * gv;
    const float hn = ov * tanhf(c);
    (p ? hbuf0 : hbuf1)[(b << 8) + u] = hn;
    // enc_out packed K-major: encK4[b][u>>2][t][u&3]
    ((float*)encK4)[(((b << 6) + (u >> 2)) << 10) + (t << 2) + (u & 3)] = hn;
    p ^= 1;
    group_barrier(cnt, tid, &gen);
  }

  // ---------------- decoder: 256 steps ----------------
  const float dbi_ = dBi[u] + dBh[u];
  const float dbf_ = dBi[256 + u] + dBh[256 + u];
  const float dbg_ = dBi[512 + u] + dBh[512 + u];
  const float dbo_ = dBi[768 + u] + dBh[768 + u];

  if (tid < 8) idxS[tid] = -1;
  if (tid < 128) ((unsigned*)maskS)[tid] = 0u;
  __syncthreads();

  for (int t = 0; t < 256; ++t) {
    // ---- phase A: decoder LSTM cell ----
    {
      const float4* hrd = (const float4*)(p ? hbuf1 : hbuf0);
      hs4[tid] = hrd[(g << 9) + tid];
      const int bb = tid >> 6, k4s = tid & 63;
      const int ix = idxS[bb];
      din4[tid] = (ix >= 0)
          ? encK4[(((((g << 3) + bb) << 6) + k4s) << 8) + ix]
          : make_float4(0.f, 0.f, 0.f, 0.f);
    }
    __syncthreads();
    float ai = dbi_, af = dbf_, ag = dbg_, ao = dbo_;
    const float4* Wi = decWi4 + u;
    const float4* Wh = decWh4 + u;
    const float4* hq = hs4 + (w << 6);
    const float4* dq = din4 + (w << 6);
#pragma unroll 2
    for (int k4 = 0; k4 < 64; ++k4) {
      const float4 hv = hq[k4];
      const float4 dv = dq[k4];
      const float4 i0 = Wi[((k4 * 4 + 0) << 8)];
      const float4 i1 = Wi[((k4 * 4 + 1) << 8)];
      const float4 i2 = Wi[((k4 * 4 + 2) << 8)];
      const float4 i3 = Wi[((k4 * 4 + 3) << 8)];
      const float4 h0 = Wh[((k4 * 4 + 0) << 8)];
      const float4 h1 = Wh[((k4 * 4 + 1) << 8)];
      const float4 h2 = Wh[((k4 * 4 + 2) << 8)];
      const float4 h3 = Wh[((k4 * 4 + 3) << 8)];
      ai += i0.x * dv.x + i1.x * dv.y + i2.x * dv.z + i3.x * dv.w;
      ai += h0.x * hv.x + h1.x * hv.y + h2.x * hv.z + h3.x * hv.w;
      af += i0.y * dv.x + i1.y * dv.y + i2.y * dv.z + i3.y * dv.w;
      af += h0.y * hv.x + h1.y * hv.y + h2.y * hv.z + h3.y * hv.w;
      ag += i0.z * dv.x + i1.z * dv.y + i2.z * dv.z + i3.z * dv.w;
      ag += h0.z * hv.x + h1.z * hv.y + h2.z * hv.z + h3.z * hv.w;
      ao += i0.w * dv.x + i1.w * dv.y + i2.w * dv.z + i3.w * dv.w;
      ao += h0.w * hv.x + h1.w * hv.y + h2.w * hv.z + h3.w * hv.w;
    }
    const float iv = sigm(ai), fv = sigm(af), gv = tanhf(ag), ov = sigm(ao);
    c = fv * c + iv * gv;
    const float hn = ov * tanhf(c);
    (p ? hbuf0 : hbuf1)[(b << 8) + u] = hn;
    p ^= 1;
    group_barrier(cnt, tid, &gen);   // new h visible to all 4 sibling blocks

    // ---- phase B: attention scores + gumbel sampling ----
    {
      const float4* hrd2 = (const float4*)(p ? hbuf1 : hbuf0);
      hs4[tid] = hrd2[(g << 9) + tid];
    }
    __syncthreads();
    const int s = u;                     // this lane's score position
    float sc = 0.f;
    const float4* E = encK4 + ((b << 6) << 8) + s;
#pragma unroll 8
    for (int k4 = 0; k4 < 64; ++k4) {
      const float4 ev = E[k4 << 8];
      const float4 hv = hq[k4];
      sc += ev.x * hv.x + ev.y * hv.y + ev.z * hv.z + ev.w * hv.w;
    }
    // gumbel noise, bit-exact threefry
    unsigned bits;
#if THREEFRY_PARTITIONABLE
    {
      unsigned kk0 = 0u, kk1 = (unsigned)t;     // fold-like split of key(42)
      tf2(0u, 42u, kk0, kk1);
      unsigned y0 = 0u, y1 = (unsigned)((b << 8) + s);
      tf2(kk0, kk1, y0, y1);
      bits = y0 ^ y1;
    }
#else
    {
      // legacy counter scheme: split -> pairs (j, j+256); bits -> (m, m+65536)
      unsigned kk0, kk1;
      if (t < 128) {
        unsigned a0 = 2u * t, a1 = 2u * t + 256u; tf2(0u, 42u, a0, a1);
        unsigned b0 = 2u * t + 1u, b1 = 2u * t + 257u; tf2(0u, 42u, b0, b1);
        kk0 = a0; kk1 = b0;
      } else {
        unsigned a0 = 2u * t - 256u, a1 = 2u * t; tf2(0u, 42u, a0, a1);
        unsigned b0 = 2u * t - 255u, b1 = 2u * t + 1u; tf2(0u, 42u, b0, b1);
        kk0 = a1; kk1 = b1;
      }
      const unsigned m = (unsigned)((b << 8) + s);
      const unsigned j = m & 65535u;
      unsigned y0 = j, y1 = j + 65536u;
      tf2(kk0, kk1, y0, y1);
      bits = (m >= 65536u) ? y1 : y0;
    }
#endif
    const float fr = __uint_as_float((bits >> 9) | 0x3f800000u) - 1.0f;
    const float uu = (fr > 0.f) ? fr : 1.17549435e-38f;
    const float gum = -logf(-logf(uu));
    const float NEG_INF = __int_as_float((int)0xff800000);
    float bv = maskS[w][l] ? NEG_INF : (sc + gum);
    int bi = s;
    // wave argmax, first-index tie-break (matches jnp.argmax)
#pragma unroll
    for (int off = 32; off; off >>= 1) {
      const float ov2 = __shfl_xor(bv, off, 64);
      const int oi2 = __shfl_xor(bi, off, 64);
      if (ov2 > bv || (ov2 == bv && oi2 < bi)) { bv = ov2; bi = oi2; }
    }
    if (l == 0)
      part[(((g << 3) + w) << 2) + us] = make_uint2(__float_as_uint(bv), (unsigned)bi);
    group_barrier(cnt, tid, &gen);
    // final cross-slice argmax (each block derives the same result)
    {
      const uint2* pw = part + (((g << 3) + w) << 2);
      const uint2 q0 = pw[0], q1 = pw[1], q2 = pw[2], q3 = pw[3];
      float v = __uint_as_float(q0.x); int fi = (int)q0.y;
      float v1 = __uint_as_float(q1.x); if (v1 > v) { v = v1; fi = (int)q1.y; }
      float v2 = __uint_as_float(q2.x); if (v2 > v) { v = v2; fi = (int)q2.y; }
      float v3 = __uint_as_float(q3.x); if (v3 > v) { v = v3; fi = (int)q3.y; }
      if (l == 0) {
        idxS[w] = fi;
        if ((fi >> 6) == us) maskS[w][fi & 63] = 1;  // owner slice sets mask
        if (us == 0) out[(b << 8) + t] = fi;
      }
    }
    __syncthreads();
  }
}

extern "C" void kernel_launch(void* const* d_in, const int* in_sizes, int n_in,
                              void* d_out, int out_size, void* d_ws, size_t ws_size,
                              hipStream_t stream) {
  (void)in_sizes; (void)n_in; (void)out_size;
  if (ws_size < WS_NEEDED) return;   // need ~139 MB scratch

  const float* inp = (const float*)d_in[0];
  const float* eWi = (const float*)d_in[1];
  const float* eWh = (const float*)d_in[2];
  const float* eBi = (const float*)d_in[3];
  const float* eBh = (const float*)d_in[4];
  const float* dWi = (const float*)d_in[5];
  const float* dWh = (const float*)d_in[6];
  const float* dBi = (const float*)d_in[7];
  const float* dBh = (const float*)d_in[8];
  int* out = (int*)d_out;
  float* wsf = (float*)d_ws;

  // zero h-state double buffer + barrier counters + argmax partials
  hipMemsetAsync(d_ws, 0, (1u << 20) + 24576u, stream);
  hipLaunchKernelGGL(repack_k, dim3(256), dim3(256), 0, stream, eWh, dWi, dWh, wsf);
  void* args[8] = { (void*)&inp, (void*)&eWi, (void*)&eBi, (void*)&eBh,
                    (void*)&dBi, (void*)&dBh, (void*)&out, (void*)&wsf };
  hipLaunchCooperativeKernel((void*)ptrnet_kernel, dim3(256), dim3(512),
                             args, 0, stream);
}

// Round 2
// 16413.142 us; speedup vs baseline: 5.7690x; 5.7690x over previous
//
#include <hip/hip_runtime.h>
#include <cstdint>
#include <cstddef>

// ============================================================================
// PointerNet: encoder LSTM (B=512,S=256,D=2,H=256) + autoregressive pointer
// decode with jax.random.categorical (threefry2x32 partitionable, key 42).
// Output: int32 indices [512][256], trajectory-exact vs JAX reference.
//
// R2 structure: NO cross-block communication. Block = 512 threads = 2 batches
// x 256 units; grid = 256 blocks (1/CU). All sync is __syncthreads(). h is
// double-buffered in LDS; cell state c lives in registers; weights stream
// from L2/L1 (repacked [k][u][4gates] float4); enc_out staged K-major-packed
// in ws for coalesced attention dots (non-temporal loads so weights stay
// L2-resident).
// ============================================================================

typedef float v4f __attribute__((ext_vector_type(4)));

#define WS_ENCW4_OFF  (2u << 20)                    // [256 k][256 u][4 g] f32
#define WS_DECWI4_OFF (3u << 20)
#define WS_DECWH4_OFF (4u << 20)
#define WS_ENCK4_OFF  (5u << 20)                    // [512 b][64 k4][256 s][4] f32
#define WS_NEEDED     ((size_t)(5u << 20) + (size_t)512 * 64 * 256 * 16)

__device__ __forceinline__ unsigned rotl32(unsigned x, int r) {
  return (x << r) | (x >> (32 - r));
}
__device__ __forceinline__ float sigm(float x) { return 1.f / (1.f + expf(-x)); }

// Threefry-2x32, 20 rounds (jax._src.prng schedule) — verified exact in R1.
__device__ __forceinline__ void tf2(unsigned k0, unsigned k1,
                                    unsigned& x0, unsigned& x1) {
  const unsigned k2 = k0 ^ k1 ^ 0x1BD11BDAu;
  x0 += k0; x1 += k1;
  x0 += x1; x1 = rotl32(x1, 13); x1 ^= x0;
  x0 += x1; x1 = rotl32(x1, 15); x1 ^= x0;
  x0 += x1; x1 = rotl32(x1, 26); x1 ^= x0;
  x0 += x1; x1 = rotl32(x1,  6); x1 ^= x0;
  x0 += k1; x1 += k2 + 1u;
  x0 += x1; x1 = rotl32(x1, 17); x1 ^= x0;
  x0 += x1; x1 = rotl32(x1, 29); x1 ^= x0;
  x0 += x1; x1 = rotl32(x1, 16); x1 ^= x0;
  x0 += x1; x1 = rotl32(x1, 24); x1 ^= x0;
  x0 += k2; x1 += k0 + 2u;
  x0 += x1; x1 = rotl32(x1, 13); x1 ^= x0;
  x0 += x1; x1 = rotl32(x1, 15); x1 ^= x0;
  x0 += x1; x1 = rotl32(x1, 26); x1 ^= x0;
  x0 += x1; x1 = rotl32(x1,  6); x1 ^= x0;
  x0 += k0; x1 += k1 + 3u;
  x0 += x1; x1 = rotl32(x1, 17); x1 ^= x0;
  x0 += x1; x1 = rotl32(x1, 29); x1 ^= x0;
  x0 += x1; x1 = rotl32(x1, 16); x1 ^= x0;
  x0 += x1; x1 = rotl32(x1, 24); x1 ^= x0;
  x0 += k1; x1 += k2 + 4u;
  x0 += x1; x1 = rotl32(x1, 13); x1 ^= x0;
  x0 += x1; x1 = rotl32(x1, 15); x1 ^= x0;
  x0 += x1; x1 = rotl32(x1, 26); x1 ^= x0;
  x0 += x1; x1 = rotl32(x1,  6); x1 ^= x0;
  x0 += k2; x1 += k0 + 5u;
}

// Repack W [1024 rows][256 k] row-major -> [k][u][gate] (float4 per (k,u)).
__global__ void repack_k(const float* __restrict__ eWh,
                         const float* __restrict__ dWi,
                         const float* __restrict__ dWh,
                         float* __restrict__ ws) {
  float* encW4 = (float*)((char*)ws + WS_ENCW4_OFF);
  float* decWi4 = (float*)((char*)ws + WS_DECWI4_OFF);
  float* decWh4 = (float*)((char*)ws + WS_DECWH4_OFF);
  const int n = blockIdx.x * blockDim.x + threadIdx.x;   // 65536 = 256k x 256u
  if (n >= 65536) return;
  const int k = n >> 8, u = n & 255;
#pragma unroll
  for (int g = 0; g < 4; ++g) {
    const int src = ((g << 8) + u) * 256 + k;
    const int dst = (n << 2) + g;
    encW4[dst] = eWh[src];
    decWi4[dst] = dWi[src];
    decWh4[dst] = dWh[src];
  }
}

__global__ void __launch_bounds__(512, 1)
ptrnet_kernel(const float* __restrict__ inp,    // [512][256][2]
              const float* __restrict__ eWi,    // [1024][2]
              const float* __restrict__ eBi, const float* __restrict__ eBh,
              const float* __restrict__ dBi, const float* __restrict__ dBh,
              int* __restrict__ out,            // [512][256]
              float* __restrict__ ws) {
  const int tid = threadIdx.x;
  const int bl = tid >> 8;              // batch within block (0/1)
  const int u  = tid & 255;             // unit / score position
  const int l  = tid & 63;
  const int wv = (tid >> 6) & 3;        // wave within bl (s-slice)
  const int b  = (blockIdx.x << 1) + bl;

  const v4f* encW4  = (const v4f*)((char*)ws + WS_ENCW4_OFF);
  const v4f* decWi4 = (const v4f*)((char*)ws + WS_DECWI4_OFF);
  const v4f* decWh4 = (const v4f*)((char*)ws + WS_DECWH4_OFF);
  v4f* encK4 = (v4f*)((char*)ws + WS_ENCK4_OFF);

  __shared__ v4f hs4[2][128];           // double buffer: [2 bl][64 k4] each
  __shared__ v4f din4[128];             // dec_in staged  [2 bl][64 k4]
  __shared__ unsigned char maskC[2][256];
  __shared__ float partV[2][4];
  __shared__ int   partI[2][4];
  __shared__ int   idxS[2];

  // ---- encoder per-lane constants ----
  const float ebi_ = eBi[u] + eBh[u];
  const float ebf_ = eBi[256 + u] + eBh[256 + u];
  const float ebg_ = eBi[512 + u] + eBh[512 + u];
  const float ebo_ = eBi[768 + u] + eBh[768 + u];
  const float wxi0 = eWi[2 * u], wxi1 = eWi[2 * u + 1];
  const float wxf0 = eWi[2 * (256 + u)], wxf1 = eWi[2 * (256 + u) + 1];
  const float wxg0 = eWi[2 * (512 + u)], wxg1 = eWi[2 * (512 + u) + 1];
  const float wxo0 = eWi[2 * (768 + u)], wxo1 = eWi[2 * (768 + u) + 1];

  if (tid < 128) hs4[0][tid] = (v4f)0.f;
  __syncthreads();

  float c = 0.f;        // cell state for (b,u), lives in a register throughout
  int p = 0;            // h read-buffer parity

  // ---------------- encoder: 256 steps ----------------
  for (int t = 0; t < 256; ++t) {
    const float2 xv = *(const float2*)(inp + ((b << 8) + t) * 2);
    float ai = ebi_ + wxi0 * xv.x + wxi1 * xv.y;
    float af = ebf_ + wxf0 * xv.x + wxf1 * xv.y;
    float ag = ebg_ + wxg0 * xv.x + wxg1 * xv.y;
    float ao = ebo_ + wxo0 * xv.x + wxo1 * xv.y;
    const v4f* Wp = encW4 + u;
    const v4f* hq = &hs4[p][bl << 6];
#pragma unroll 4
    for (int k4 = 0; k4 < 64; ++k4) {
      const v4f hv = hq[k4];
      const v4f w0 = Wp[((k4 * 4 + 0) << 8)];
      const v4f w1 = Wp[((k4 * 4 + 1) << 8)];
      const v4f w2 = Wp[((k4 * 4 + 2) << 8)];
      const v4f w3 = Wp[((k4 * 4 + 3) << 8)];
      ai += w0.x * hv.x + w1.x * hv.y + w2.x * hv.z + w3.x * hv.w;
      af += w0.y * hv.x + w1.y * hv.y + w2.y * hv.z + w3.y * hv.w;
      ag += w0.z * hv.x + w1.z * hv.y + w2.z * hv.z + w3.z * hv.w;
      ao += w0.w * hv.x + w1.w * hv.y + w2.w * hv.z + w3.w * hv.w;
    }
    const float iv = sigm(ai), fv = sigm(af), gv = tanhf(ag), ov = sigm(ao);
    c = fv * c + iv * gv;
    const float hn = ov * tanhf(c);
    ((float*)hs4[p ^ 1])[(bl << 8) + u] = hn;                 // other buffer: no hazard
    ((float*)encK4)[(((b << 6) + (u >> 2)) << 10) + (t << 2) + (u & 3)] = hn;
    p ^= 1;
    __syncthreads();
  }

  // ---------------- decoder: 256 steps ----------------
  const float dbi_ = dBi[u] + dBh[u];
  const float dbf_ = dBi[256 + u] + dBh[256 + u];
  const float dbg_ = dBi[512 + u] + dBh[512 + u];
  const float dbo_ = dBi[768 + u] + dBh[768 + u];

  if (tid < 2) idxS[tid] = -1;
  maskC[bl][u] = 0;
  __syncthreads();

  for (int t = 0; t < 256; ++t) {
    // ---- stage dec_in = enc_out[b, idx] (or 0 at t=0) ----
    if (tid < 128) {
      const int bb = tid >> 6, k4 = tid & 63;
      const int ix = idxS[bb];
      v4f dv = (v4f)0.f;
      if (ix >= 0)
        dv = __builtin_nontemporal_load(
            &encK4[(((((blockIdx.x << 1) + bb) << 6) + k4) << 8) + ix]);
      din4[tid] = dv;
    }
    __syncthreads();

    // ---- decoder LSTM cell ----
    float ai = dbi_, af = dbf_, ag = dbg_, ao = dbo_;
    const v4f* Wi = decWi4 + u;
    const v4f* Wh = decWh4 + u;
    const v4f* hq = &hs4[p][bl << 6];
    const v4f* dq = &din4[bl << 6];
#pragma unroll 2
    for (int k4 = 0; k4 < 64; ++k4) {
      const v4f hv = hq[k4];
      const v4f dv = dq[k4];
      const v4f i0 = Wi[((k4 * 4 + 0) << 8)];
      const v4f i1 = Wi[((k4 * 4 + 1) << 8)];
      const v4f i2 = Wi[((k4 * 4 + 2) << 8)];
      const v4f i3 = Wi[((k4 * 4 + 3) << 8)];
      const v4f h0 = Wh[((k4 * 4 + 0) << 8)];
      const v4f h1 = Wh[((k4 * 4 + 1) << 8)];
      const v4f h2 = Wh[((k4 * 4 + 2) << 8)];
      const v4f h3 = Wh[((k4 * 4 + 3) << 8)];
      ai += i0.x * dv.x + i1.x * dv.y + i2.x * dv.z + i3.x * dv.w;
      ai += h0.x * hv.x + h1.x * hv.y + h2.x * hv.z + h3.x * hv.w;
      af += i0.y * dv.x + i1.y * dv.y + i2.y * dv.z + i3.y * dv.w;
      af += h0.y * hv.x + h1.y * hv.y + h2.y * hv.z + h3.y * hv.w;
      ag += i0.z * dv.x + i1.z * dv.y + i2.z * dv.z + i3.z * dv.w;
      ag += h0.z * hv.x + h1.z * hv.y + h2.z * hv.z + h3.z * hv.w;
      ao += i0.w * dv.x + i1.w * dv.y + i2.w * dv.z + i3.w * dv.w;
      ao += h0.w * hv.x + h1.w * hv.y + h2.w * hv.z + h3.w * hv.w;
    }
    const float iv = sigm(ai), fv = sigm(af), gv = tanhf(ag), ov = sigm(ao);
    c = fv * c + iv * gv;
    const float hn = ov * tanhf(c);
    ((float*)hs4[p ^ 1])[(bl << 8) + u] = hn;
    p ^= 1;
    __syncthreads();                      // new h visible to whole block

    // ---- attention scores + gumbel sampling ----
    const int s = u;
    float sc = 0.f;
    const v4f* hq2 = &hs4[p][bl << 6];
    const v4f* E = encK4 + (b << 14) + s;
#pragma unroll 8
    for (int k4 = 0; k4 < 64; ++k4) {
      const v4f ev = __builtin_nontemporal_load(&E[k4 << 8]);
      const v4f hv = hq2[k4];
      sc += ev.x * hv.x + ev.y * hv.y + ev.z * hv.z + ev.w * hv.w;
    }
    // threefry2x32 partitionable: key_t = tf2(key42; 0,t); bits = x0^x1
    unsigned bits;
    {
      unsigned kk0 = 0u, kk1 = (unsigned)t;
      tf2(0u, 42u, kk0, kk1);
      unsigned y0 = 0u, y1 = (unsigned)((b << 8) + s);
      tf2(kk0, kk1, y0, y1);
      bits = y0 ^ y1;
    }
    const float fr = __uint_as_float((bits >> 9) | 0x3f800000u) - 1.0f;
    const float uu = (fr > 0.f) ? fr : 1.17549435e-38f;
    const float gum = -logf(-logf(uu));
    const float NEG_INF = __int_as_float((int)0xff800000);
    float bv = maskC[bl][s] ? NEG_INF : (sc + gum);
    int bi = s;
    // wave argmax, first-index tie-break (matches jnp.argmax)
#pragma unroll
    for (int off = 32; off; off >>= 1) {
      const float ov2 = __shfl_xor(bv, off, 64);
      const int oi2 = __shfl_xor(bi, off, 64);
      if (ov2 > bv || (ov2 == bv && oi2 < bi)) { bv = ov2; bi = oi2; }
    }
    if (l == 0) { partV[bl][wv] = bv; partI[bl][wv] = bi; }
    __syncthreads();
    if ((tid & 255) == 0) {               // one thread per batch
      float v = partV[bl][0]; int fi = partI[bl][0];
#pragma unroll
      for (int j = 1; j < 4; ++j) {
        const float vj = partV[bl][j];
        if (vj > v) { v = vj; fi = partI[bl][j]; }
      }
      idxS[bl] = fi;
      maskC[bl][fi] = 1;
      out[(b << 8) + t] = fi;
    }
    __syncthreads();                      // idxS/mask visible for next staging
  }
}

extern "C" void kernel_launch(void* const* d_in, const int* in_sizes, int n_in,
                              void* d_out, int out_size, void* d_ws, size_t ws_size,
                              hipStream_t stream) {
  (void)in_sizes; (void)n_in; (void)out_size;
  if (ws_size < WS_NEEDED) return;   // need ~139 MB scratch

  const float* inp = (const float*)d_in[0];
  const float* eWi = (const float*)d_in[1];
  const float* eWh = (const float*)d_in[2];
  const float* eBi = (const float*)d_in[3];
  const float* eBh = (const float*)d_in[4];
  const float* dWi = (const float*)d_in[5];
  const float* dWh = (const float*)d_in[6];
  const float* dBi = (const float*)d_in[7];
  const float* dBh = (const float*)d_in[8];
  int* out = (int*)d_out;
  float* wsf = (float*)d_ws;

  hipLaunchKernelGGL(repack_k, dim3(256), dim3(256), 0, stream, eWh, dWi, dWh, wsf);
  hipLaunchKernelGGL(ptrnet_kernel, dim3(256), dim3(512), 0, stream,
                     inp, eWi, eBi, eBh, dBi, dBh, out, wsf);
}